// Round 2
// baseline (16329.314 us; speedup 1.0000x reference)
//
#include <hip/hip_runtime.h>
#include <hip/hip_bf16.h>

// LSTM decoder w/ argmax feedback. V=10000 E=512 H=512 B=64 T=128.
// Dual-mode: detects at runtime whether float inputs are fp32 or bf16.
// h/c/inp kept fp32; MFMA GEMMs use split-bf16 (hi/lo) passes so logits
// match the np fp32 reference to ~1e-5 (argmax-stable feedback).

#define VSZ 10000
#define ESZ 512
#define HSZ 512
#define BSZ 64
#define TSZ 128
#define NSTEP (TSZ - 1)
#define NTILE 157   // ceil(10000/64) vocab tiles

typedef short bf16x8 __attribute__((ext_vector_type(8)));
typedef float f32x4 __attribute__((ext_vector_type(4)));

struct alignas(8) us4_t { unsigned short s[4]; };

#define NEG_INF (-3.402823466e38f)

__device__ __forceinline__ float bf2f(unsigned short u) {
    union { unsigned int i; float f; } c;
    c.i = ((unsigned int)u) << 16;
    return c.f;
}
__device__ __forceinline__ unsigned short f2bf(float f) {
    union { float f; unsigned int i; } c;
    c.f = f;
    unsigned int b = c.i;
    b += 0x7FFFu + ((b >> 16) & 1u);   // RNE (finite inputs only)
    return (unsigned short)(b >> 16);
}
__device__ __forceinline__ float sigmoidf_(float x) {
    return 1.0f / (1.0f + expf(-x));
}
__device__ __forceinline__ int imin_(int a, int b) { return a < b ? a : b; }
__device__ __forceinline__ int imax_(int a, int b) { return a > b ? a : b; }

// pack 8 fp32 -> bf16 (RNE); exact if values already bf16-representable
__device__ __forceinline__ bf16x8 pack8(const float* p) {
    float4 x = *(const float4*)p;
    float4 y = *(const float4*)(p + 4);
    float v[8] = {x.x, x.y, x.z, x.w, y.x, y.y, y.z, y.w};
    bf16x8 r;
    #pragma unroll
    for (int j = 0; j < 8; j++) r[j] = (short)f2bf(v[j]);
    return r;
}
// split 8 fp32 into bf16 hi + bf16 lo (hi+lo ~ x to ~2^-17 rel)
__device__ __forceinline__ void split8(const float* p, bf16x8& hi, bf16x8& lo) {
    float4 x = *(const float4*)p;
    float4 y = *(const float4*)(p + 4);
    float v[8] = {x.x, x.y, x.z, x.w, y.x, y.y, y.z, y.w};
    #pragma unroll
    for (int j = 0; j < 8; j++) {
        unsigned short h = f2bf(v[j]);
        hi[j] = (short)h;
        lo[j] = (short)f2bf(v[j] - bf2f(h));
    }
}

// ---- detector: mode (fp32 vs bf16 float arrays) + use_label canonicalize ----
__global__ __launch_bounds__(256) void det_kernel(
        const void* wout, const void* usel_raw, int* flags, int* usel) {
    __shared__ int s_bad, s_cnt;
    int tid = threadIdx.x;
    if (tid == 0) { s_bad = 0; s_cnt = 0; }
    __syncthreads();
    // bf16 W_out has |w| <= 0.045 (exp <= 0x7A). fp32 read as ushorts has
    // random low halves: exponent >= 0x7D (|v|>=0.25) appears w.p. ~0.3/elem.
    unsigned short u = ((const unsigned short*)wout)[tid];
    int e = (u >> 7) & 0xFF;
    if (e >= 0x7D) atomicOr(&s_bad, 1);
    if (tid < 32) {
        int word = ((const int*)usel_raw)[tid];
        if (word == 0 || word == 1) atomicAdd(&s_cnt, 1);
    }
    __syncthreads();
    int mode = s_bad ? 1 : 0;
    int as_int = (s_cnt == 32) ? 1 : 0;
    if (tid == 0) { flags[0] = mode; flags[1] = as_int; }
    if (tid < TSZ) {
        int v;
        if (as_int) v = ((const int*)usel_raw)[tid];
        else        v = (int)((const unsigned char*)usel_raw)[tid];
        usel[tid] = v ? 1 : 0;
    }
}

// ---- base[g,b] = b_ih[g]+b_hh[g]+ctx[b,:]@W_ih[g,0:512]; lives in d_out t=0 slice ----
__global__ __launch_bounds__(256) void base_kernel(
        const void* ctx, const void* Wih, const void* bih, const void* bhh,
        const int* flags, char* outb) {
    int tid = threadIdx.x;
    int b = tid & 63;
    int gi = tid >> 6;
    int g = blockIdx.x * 4 + gi;
    float acc;
    size_t rowb;
    if (flags[0] == 0) {
        rowb = 2560000u;
        const unsigned short* wr = (const unsigned short*)Wih + (size_t)g * 1024;
        const unsigned short* cr = (const unsigned short*)ctx + (size_t)b * HSZ;
        acc = bf2f(((const unsigned short*)bih)[g]) + bf2f(((const unsigned short*)bhh)[g]);
        for (int k = 0; k < HSZ; k += 8) {
            #pragma unroll
            for (int u = 0; u < 8; u++) acc += bf2f(cr[k + u]) * bf2f(wr[k + u]);
        }
    } else {
        rowb = 5120000u;
        const float* wr = (const float*)Wih + (size_t)g * 1024;
        const float* cr = (const float*)ctx + (size_t)b * HSZ;
        acc = ((const float*)bih)[g] + ((const float*)bhh)[g];
        for (int k = 0; k < HSZ; k += 8) {
            #pragma unroll
            for (int u = 0; u < 8; u++) acc += cr[k + u] * wr[k + u];
        }
    }
    ((float*)(outb + (size_t)b * rowb))[g] = acc;
}

// ---- init: c=h0=ctx (fp32); inp = emb[labels[:,0]] (fp32) ----
__global__ __launch_bounds__(256) void init_kernel(
        const void* ctx, const void* emb, const int* labels, const int* flags,
        float* c, float* h0, float* inp) {
    int mode = flags[0];
    int i = blockIdx.x * 256 + threadIdx.x;   // 32768
    int b = i >> 9, j = i & 511;
    float cv = mode ? ((const float*)ctx)[i] : bf2f(((const unsigned short*)ctx)[i]);
    c[i] = cv;
    h0[i] = cv;
    int lab = imin_(imax_(labels[b * TSZ], 0), VSZ - 1);
    inp[i] = mode ? ((const float*)emb)[(size_t)lab * ESZ + j]
                  : bf2f(((const unsigned short*)emb)[(size_t)lab * ESZ + j]);
}

// ---- per-step LSTM cell: split-bf16 MFMA gates + fused elementwise ----
template<int MODE>
__device__ __forceinline__ void cell_body(
        const void* Wih, const void* Whh, const char* outb,
        const float* inp, const float* hin, float* hout, float* c) {
    __shared__ float lds[4][16][64];
    const size_t rowb = MODE ? 5120000u : 2560000u;
    int tid = threadIdx.x;
    int w = tid >> 6;          // gate: 0=i 1=f 2=g 3=o
    int lane = tid & 63;
    int col = lane & 15;
    int quad = lane >> 4;
    int j0 = blockIdx.x * 16;
    int grow = w * 512 + j0 + col;

    f32x4 acc[4];
    #pragma unroll
    for (int nt = 0; nt < 4; nt++) acc[nt] = (f32x4){0.f, 0.f, 0.f, 0.f};

    if (MODE == 0) {
        const unsigned short* Arow = (const unsigned short*)Wih + (size_t)grow * 1024 + 512;
        for (int k0 = 0; k0 < 512; k0 += 32) {
            bf16x8 a = *(const bf16x8*)(Arow + k0 + quad * 8);
            #pragma unroll
            for (int nt = 0; nt < 4; nt++) {
                bf16x8 bh = pack8(inp + (nt * 16 + col) * 512 + k0 + quad * 8); // exact bf16
                acc[nt] = __builtin_amdgcn_mfma_f32_16x16x32_bf16(a, bh, acc[nt], 0, 0, 0);
            }
        }
        const unsigned short* Arow2 = (const unsigned short*)Whh + (size_t)grow * 512;
        for (int k0 = 0; k0 < 512; k0 += 32) {
            bf16x8 a = *(const bf16x8*)(Arow2 + k0 + quad * 8);
            #pragma unroll
            for (int nt = 0; nt < 4; nt++) {
                bf16x8 bh, bl;
                split8(hin + (nt * 16 + col) * 512 + k0 + quad * 8, bh, bl);
                acc[nt] = __builtin_amdgcn_mfma_f32_16x16x32_bf16(a, bh, acc[nt], 0, 0, 0);
                acc[nt] = __builtin_amdgcn_mfma_f32_16x16x32_bf16(a, bl, acc[nt], 0, 0, 0);
            }
        }
    } else {
        const float* Arow = (const float*)Wih + (size_t)grow * 1024 + 512;
        for (int k0 = 0; k0 < 512; k0 += 32) {
            bf16x8 ah, al;
            split8(Arow + k0 + quad * 8, ah, al);
            #pragma unroll
            for (int nt = 0; nt < 4; nt++) {
                bf16x8 bh, bl;
                split8(inp + (nt * 16 + col) * 512 + k0 + quad * 8, bh, bl);
                acc[nt] = __builtin_amdgcn_mfma_f32_16x16x32_bf16(ah, bh, acc[nt], 0, 0, 0);
                acc[nt] = __builtin_amdgcn_mfma_f32_16x16x32_bf16(ah, bl, acc[nt], 0, 0, 0);
                acc[nt] = __builtin_amdgcn_mfma_f32_16x16x32_bf16(al, bh, acc[nt], 0, 0, 0);
            }
        }
        const float* Arow2 = (const float*)Whh + (size_t)grow * 512;
        for (int k0 = 0; k0 < 512; k0 += 32) {
            bf16x8 ah, al;
            split8(Arow2 + k0 + quad * 8, ah, al);
            #pragma unroll
            for (int nt = 0; nt < 4; nt++) {
                bf16x8 bh, bl;
                split8(hin + (nt * 16 + col) * 512 + k0 + quad * 8, bh, bl);
                acc[nt] = __builtin_amdgcn_mfma_f32_16x16x32_bf16(ah, bh, acc[nt], 0, 0, 0);
                acc[nt] = __builtin_amdgcn_mfma_f32_16x16x32_bf16(ah, bl, acc[nt], 0, 0, 0);
                acc[nt] = __builtin_amdgcn_mfma_f32_16x16x32_bf16(al, bh, acc[nt], 0, 0, 0);
            }
        }
    }
    // C/D: col=lane&15 (batch), row=quad*4+r (gate j-offset)  [m89/m91]
    #pragma unroll
    for (int nt = 0; nt < 4; nt++) {
        #pragma unroll
        for (int r = 0; r < 4; r++) {
            int row = quad * 4 + r;
            int b = nt * 16 + col;
            float bs = ((const float*)(outb + (size_t)b * rowb))[w * 512 + j0 + row];
            lds[w][row][b] = acc[nt][r] + bs;
        }
    }
    __syncthreads();
    for (int i = tid; i < 1024; i += 256) {
        int jl = i >> 6, b = i & 63, j = j0 + jl;
        float iv = sigmoidf_(lds[0][jl][b]);
        float fv = sigmoidf_(lds[1][jl][b]);
        float gv = tanhf(lds[2][jl][b]);
        float ov = sigmoidf_(lds[3][jl][b]);
        float c2 = fv * c[b * 512 + j] + iv * gv;
        c[b * 512 + j] = c2;
        hout[b * 512 + j] = ov * tanhf(c2);   // fp32 h, like the reference
    }
}

__global__ __launch_bounds__(256) void cell_kernel(
        const void* Wih, const void* Whh, char* outb, const float* inp,
        const float* hin, float* hout, float* c, const int* flags) {
    if (flags[0] == 0) cell_body<0>(Wih, Whh, outb, inp, hin, hout, c);
    else               cell_body<1>(Wih, Whh, outb, inp, hin, hout, c);
}

// ---- per-step logits + per-block partial argmax ----
template<int MODE>
__device__ __forceinline__ void out_body(
        const void* Wout, const void* bout, const float* h, void* outv,
        float* pval, int* pidx, int t) {
    __shared__ float sv[4][64];
    __shared__ int   si[4][64];
    int tid = threadIdx.x;
    int w = tid >> 6, lane = tid & 63, col = lane & 15, quad = lane >> 4;
    int v0 = blockIdx.x * 64 + w * 16;
    int arow = imin_(v0 + col, VSZ - 1);

    f32x4 acc[4];
    #pragma unroll
    for (int nt = 0; nt < 4; nt++) acc[nt] = (f32x4){0.f, 0.f, 0.f, 0.f};

    if (MODE == 0) {
        const unsigned short* A = (const unsigned short*)Wout + (size_t)arow * 512;
        for (int k0 = 0; k0 < 512; k0 += 32) {
            bf16x8 a = *(const bf16x8*)(A + k0 + quad * 8);
            #pragma unroll
            for (int nt = 0; nt < 4; nt++) {
                bf16x8 bh, bl;
                split8(h + (nt * 16 + col) * 512 + k0 + quad * 8, bh, bl);
                acc[nt] = __builtin_amdgcn_mfma_f32_16x16x32_bf16(a, bh, acc[nt], 0, 0, 0);
                acc[nt] = __builtin_amdgcn_mfma_f32_16x16x32_bf16(a, bl, acc[nt], 0, 0, 0);
            }
        }
    } else {
        const float* A = (const float*)Wout + (size_t)arow * 512;
        for (int k0 = 0; k0 < 512; k0 += 32) {
            bf16x8 ah, al;
            split8(A + k0 + quad * 8, ah, al);
            #pragma unroll
            for (int nt = 0; nt < 4; nt++) {
                bf16x8 bh, bl;
                split8(h + (nt * 16 + col) * 512 + k0 + quad * 8, bh, bl);
                acc[nt] = __builtin_amdgcn_mfma_f32_16x16x32_bf16(ah, bh, acc[nt], 0, 0, 0);
                acc[nt] = __builtin_amdgcn_mfma_f32_16x16x32_bf16(ah, bl, acc[nt], 0, 0, 0);
                acc[nt] = __builtin_amdgcn_mfma_f32_16x16x32_bf16(al, bh, acc[nt], 0, 0, 0);
            }
        }
    }

    int vbase = v0 + quad * 4;
    #pragma unroll
    for (int nt = 0; nt < 4; nt++) {
        int b = nt * 16 + col;
        float bv = NEG_INF;
        int bi = 0;
        float vals[4];
        #pragma unroll
        for (int r = 0; r < 4; r++) {
            int v = vbase + r;
            int vc = imin_(v, VSZ - 1);
            float bias = MODE ? ((const float*)bout)[vc]
                              : bf2f(((const unsigned short*)bout)[vc]);
            float val = acc[nt][r] + bias;
            vals[r] = val;
            if (v < VSZ && val > bv) { bv = val; bi = v; }
        }
        size_t obase = ((size_t)b * TSZ + t) * VSZ;
        if (MODE == 0) {
            us4_t pack;
            #pragma unroll
            for (int r = 0; r < 4; r++) pack.s[r] = f2bf(vals[r]);
            if (vbase + 3 < VSZ) {
                *(us4_t*)((unsigned short*)outv + obase + vbase) = pack;
            } else {
                for (int r = 0; r < 4; r++)
                    if (vbase + r < VSZ) ((unsigned short*)outv)[obase + vbase + r] = pack.s[r];
            }
        } else {
            if (vbase + 3 < VSZ) {
                float4 f4; f4.x = vals[0]; f4.y = vals[1]; f4.z = vals[2]; f4.w = vals[3];
                *(float4*)((float*)outv + obase + vbase) = f4;
            } else {
                for (int r = 0; r < 4; r++)
                    if (vbase + r < VSZ) ((float*)outv)[obase + vbase + r] = vals[r];
            }
        }
        #pragma unroll
        for (int off = 16; off < 64; off <<= 1) {
            float ov = __shfl_xor(bv, off);
            int oi = __shfl_xor(bi, off);
            if (ov > bv || (ov == bv && oi < bi)) { bv = ov; bi = oi; }
        }
        if (quad == 0) { sv[w][b] = bv; si[w][b] = bi; }
    }
    __syncthreads();
    if (tid < 64) {
        float bv = sv[0][tid];
        int bi = si[0][tid];
        #pragma unroll
        for (int w2 = 1; w2 < 4; w2++) {
            float v2 = sv[w2][tid];
            int i2 = si[w2][tid];
            if (v2 > bv || (v2 == bv && i2 < bi)) { bv = v2; bi = i2; }
        }
        pval[blockIdx.x * 64 + tid] = bv;
        pidx[blockIdx.x * 64 + tid] = bi;
    }
}

__global__ __launch_bounds__(256) void out_kernel(
        const void* Wout, const void* bout, const float* h, void* outv,
        float* pval, int* pidx, int t, const int* flags) {
    if (flags[0] == 0) out_body<0>(Wout, bout, h, outv, pval, pidx, t);
    else               out_body<1>(Wout, bout, h, outv, pval, pidx, t);
}

// ---- finalize argmax, build next input (fp32) ----
__global__ __launch_bounds__(1024) void pick_kernel(
        const float* __restrict__ pval, const int* __restrict__ pidx,
        const void* emb, const int* __restrict__ labels,
        const int* __restrict__ usel, float* __restrict__ inp, int t,
        const int* __restrict__ flags) {
    __shared__ float svv[64][4];
    __shared__ int   sii[64][4];
    __shared__ int   pred[64];
    int mode = flags[0];
    int tid = threadIdx.x;
    if (tid < 256) {
        int b = tid >> 2, q = tid & 3;
        float bv = NEG_INF;
        int bi = 0;
        for (int wt = q; wt < NTILE; wt += 4) {
            float v = pval[wt * 64 + b];
            int ix = pidx[wt * 64 + b];
            if (v > bv || (v == bv && ix < bi)) { bv = v; bi = ix; }
        }
        svv[b][q] = bv;
        sii[b][q] = bi;
    }
    __syncthreads();
    if (tid < 64) {
        float v = svv[tid][0];
        int ix = sii[tid][0];
        #pragma unroll
        for (int q2 = 1; q2 < 4; q2++) {
            float v2 = svv[tid][q2];
            int i2 = sii[tid][q2];
            if (v2 > v || (v2 == v && i2 < ix)) { v = v2; ix = i2; }
        }
        int lab = labels[tid * TSZ + t];
        int p = usel[t] ? lab : ix;
        pred[tid] = imin_(imax_(p, 0), VSZ - 1);
    }
    __syncthreads();
    // inp[b][0:512] = emb[pred[b]]; 8192 float4 chunks
    for (int i = tid; i < BSZ * ESZ / 4; i += 1024) {
        int b2 = i >> 7;
        int ch = i & 127;
        float4 f;
        if (mode) {
            f = ((const float4*)emb)[(size_t)pred[b2] * 128 + ch];
        } else {
            us4_t u = ((const us4_t*)emb)[(size_t)pred[b2] * 128 + ch];
            f.x = bf2f(u.s[0]); f.y = bf2f(u.s[1]); f.z = bf2f(u.s[2]); f.w = bf2f(u.s[3]);
        }
        ((float4*)inp)[i] = f;
    }
}

// ---- zero the t=0 output slice (also wipes the base scratch living there) ----
__global__ void zero_t0_kernel(char* outb, const int* flags) {
    int i = blockIdx.x * 256 + threadIdx.x;
    uint4 z = make_uint4(0u, 0u, 0u, 0u);
    if (flags[0]) {
        if (i < 160000) {
            int b = i / 2500, ch = i - b * 2500;
            *((uint4*)(outb + (size_t)b * 5120000u) + ch) = z;
        }
    } else {
        if (i < 80000) {
            int b = i / 1250, ch = i - b * 1250;
            *((uint4*)(outb + (size_t)b * 2560000u) + ch) = z;
        }
    }
}

extern "C" void kernel_launch(void* const* d_in, const int* in_sizes, int n_in,
                              void* d_out, int out_size, void* d_ws, size_t ws_size,
                              hipStream_t stream) {
    const void* ctx      = d_in[0];
    const int*  labels   = (const int*)d_in[1];
    const void* usel_raw = d_in[2];
    const void* emb      = d_in[3];
    const void* Wih      = d_in[4];
    const void* Whh      = d_in[5];
    const void* bih      = d_in[6];
    const void* bhh      = d_in[7];
    const void* Wout     = d_in[8];
    const void* bout     = d_in[9];
    char* outb = (char*)d_out;

    char* ws = (char*)d_ws;                       // total 605,696 B
    int*   flags = (int*)ws;                      // 256 B
    int*   usel  = (int*)(ws + 256);              // 512 B
    float* pval  = (float*)(ws + 1024);           // 157*64*4 = 40192
    int*   pidx  = (int*)(ws + 41216);            // 40192
    float* c     = (float*)(ws + 81408);          // 131072
    float* h0    = (float*)(ws + 212480);         // 131072
    float* h1    = (float*)(ws + 343552);         // 131072
    float* inp   = (float*)(ws + 474624);         // 131072

    det_kernel<<<1, 256, 0, stream>>>(Wout, usel_raw, flags, usel);
    base_kernel<<<512, 256, 0, stream>>>(ctx, Wih, bih, bhh, flags, outb);
    init_kernel<<<128, 256, 0, stream>>>(ctx, emb, labels, flags, c, h0, inp);

    for (int k = 0; k < NSTEP; ++k) {
        float* hin  = (k & 1) ? h1 : h0;
        float* hout = (k & 1) ? h0 : h1;
        cell_kernel<<<32, 256, 0, stream>>>(Wih, Whh, outb, inp, hin, hout, c, flags);
        out_kernel<<<NTILE, 256, 0, stream>>>(Wout, bout, hout, (void*)outb,
                                              pval, pidx, k + 1, flags);
        pick_kernel<<<1, 1024, 0, stream>>>(pval, pidx, emb, labels, usel, inp,
                                            k + 1, flags);
    }
    zero_t0_kernel<<<626, 256, 0, stream>>>(outb, flags);
}